// Round 7
// baseline (424.212 us; speedup 1.0000x reference)
//
#include <hip/hip_runtime.h>
#include <hip/hip_bf16.h>
#include <math.h>

// B=512, S=512, C=96. One block (2 waves, 128 thr) per chain; thread j<96
// owns column j; E=exp(T) column = 48 half2 VGPRs/lane. State = UNNORMALIZED
// scaled probs w (fp16 in LDS); exact exponent K of max(w) travels through
// the same barrier, folded via ldexp (feedback-free; exact integer sumk).
// R7: force register allocation. R3-R6 all plateaued at ~1380 cyc/step with
// VGPR_Count 60-100: allocator targeted high occupancy, pushed ecol to AGPRs
// (copy per use) and serialized the 12 ds_read_b128 into ~6 chunked round
// trips (~120 cyc each). Fix: amdgpu_waves_per_eu(1,1) (budget for the real
// occupancy: 1 wave/SIMD) + an inline-asm block issuing all 12 ds_read_b128
// with forced-live b128 tuple outputs and a single lgkmcnt(0).

#define BATCH 512
#define SEQ   512
#define NC    96
#define NTHR  128
#define LN2   0.69314718055994531f

typedef __fp16 half2v __attribute__((ext_vector_type(2)));
typedef unsigned uint4v __attribute__((ext_vector_type(4)));

// barrier that does NOT drain vmcnt (keeps emission prefetch in flight)
#define BARRIER() asm volatile("s_waitcnt lgkmcnt(0)\n\ts_barrier" ::: "memory")

// ---- DPP wave64 reduce (result broadcast via readlane 63) -------------
#define DPP_STEP_F(v, op, ctrl)                                              \
    v = op(v, __int_as_float(__builtin_amdgcn_update_dpp(                    \
            __float_as_int(v), __float_as_int(v), (ctrl), 0xf, 0xf, false)))

__device__ __forceinline__ float wave_max_all(float v) {
    DPP_STEP_F(v, fmaxf, 0x111);
    DPP_STEP_F(v, fmaxf, 0x112);
    DPP_STEP_F(v, fmaxf, 0x114);
    DPP_STEP_F(v, fmaxf, 0x118);
    DPP_STEP_F(v, fmaxf, 0x142);
    DPP_STEP_F(v, fmaxf, 0x143);
    return __int_as_float(__builtin_amdgcn_readlane(__float_as_int(v), 63));
}
__device__ __forceinline__ float fadd_(float a, float b) { return a + b; }
__device__ __forceinline__ float wave_sum_all(float v) {
    DPP_STEP_F(v, fadd_, 0x111);
    DPP_STEP_F(v, fadd_, 0x112);
    DPP_STEP_F(v, fadd_, 0x114);
    DPP_STEP_F(v, fadd_, 0x118);
    DPP_STEP_F(v, fadd_, 0x142);
    DPP_STEP_F(v, fadd_, 0x143);
    return __int_as_float(__builtin_amdgcn_readlane(__float_as_int(v), 63));
}

__global__ __launch_bounds__(NTHR, 1)
__attribute__((amdgpu_waves_per_eu(1, 1)))
void crf_llh_kernel(const float* __restrict__ em,      // (B,S,C)
                    const int*   __restrict__ tags,    // (B,S)
                    const int*   __restrict__ masks,   // (B,S)
                    const float* __restrict__ startT,  // (C)
                    const float* __restrict__ endT,    // (C)
                    const float* __restrict__ trans,   // (C,C)
                    float*       __restrict__ out)     // scalar
{
    const int b    = blockIdx.x;
    const int tid  = threadIdx.x;     // 0..127; column index
    const int lane = tid & 63;
    const int wid  = tid >> 6;
    const bool active = (tid < NC);
    const int jc = active ? tid : 0;

    __shared__ __align__(16) __fp16 qsh[2][128];  // double-buffered state (w)
    __shared__ float maxsh[2][2];                 // [parity][wave]
    __shared__ float redn[2], redm[2], redd[2];

    const float* em_b    = em    + (size_t)b * SEQ * NC;
    const int*   tags_b  = tags  + b * SEQ;
    const int*   masks_b = masks + b * SEQ;

    // ---- E column jc as 48 half2 (pairs along i) — 48 VGPRs
    half2v ecol[48];
    #pragma unroll
    for (int k = 0; k < 48; ++k) {
        ecol[k] = __builtin_amdgcn_cvt_pkrtz(
            __expf(trans[(2 * k)     * NC + jc]),
            __expf(trans[(2 * k + 1) * NC + jc]));
    }

    // ---- init: alpha0 = start + em[0]; M0 = exact block max
    const float al0 = startT[jc] + em_b[jc];
    {
        const float wm = wave_max_all(active ? al0 : -1e30f);
        if (lane == 0) maxsh[0][wid] = wm;
    }
    BARRIER();
    const float M0 = fmaxf(maxsh[0][0], maxsh[0][1]);
    float wreg = active ? __expf(al0 - M0) : 0.f;   // max(wreg) == 1.0
    qsh[1][tid] = (__fp16)wreg;                     // step 1 reads buffer 1
    BARRIER();

    int K    = 1;   // exponent of max(w) currently in qsh: 1.0 in [2^0,2^1)
    int sumk = 0;   // exact accumulated exponent

    // ---- prefetch pipeline (distance 3)
    float emA = em_b[1 * NC + jc];
    float emB = em_b[2 * NC + jc];
    float emC = em_b[3 * NC + jc];
    int mkA = masks_b[1], mkB = masks_b[2], mkC = masks_b[3];

    for (int s = 1; s < SEQ; ++s) {
        const int rb = s & 1;
        const int sp = (s + 3 < SEQ) ? (s + 3) : (SEQ - 1);
        const float emN = em_b[sp * NC + jc];
        const int   mkN = masks_b[sp];

        // ---- forced-pipelined load of all 12 q vectors (48 VGPRs live)
        const unsigned qaddr =
            (unsigned)(uintptr_t)(&qsh[rb][0]);
        uint4v q0, q1, q2, q3, q4, q5, q6, q7, q8, q9, q10, q11;
        asm volatile(
            "ds_read_b128 %0, %12 offset:0\n\t"
            "ds_read_b128 %1, %12 offset:16\n\t"
            "ds_read_b128 %2, %12 offset:32\n\t"
            "ds_read_b128 %3, %12 offset:48\n\t"
            "ds_read_b128 %4, %12 offset:64\n\t"
            "ds_read_b128 %5, %12 offset:80\n\t"
            "ds_read_b128 %6, %12 offset:96\n\t"
            "ds_read_b128 %7, %12 offset:112\n\t"
            "ds_read_b128 %8, %12 offset:128\n\t"
            "ds_read_b128 %9, %12 offset:144\n\t"
            "ds_read_b128 %10, %12 offset:160\n\t"
            "ds_read_b128 %11, %12 offset:176\n\t"
            "s_waitcnt lgkmcnt(0)"
            : "=&v"(q0), "=&v"(q1), "=&v"(q2), "=&v"(q3),
              "=&v"(q4), "=&v"(q5), "=&v"(q6), "=&v"(q7),
              "=&v"(q8), "=&v"(q9), "=&v"(q10), "=&v"(q11)
            : "v"(qaddr)
            : "memory");
        uint4v qv[12] = {q0, q1, q2, q3, q4, q5, q6, q7, q8, q9, q10, q11};

        // dot: U_j = sum_i w_i * E[i][jc]  (48 fdot2, 6 indep chains)
        float acc[6] = {0.f, 0.f, 0.f, 0.f, 0.f, 0.f};
        #pragma unroll
        for (int t = 0; t < 12; ++t) {
            const half2v qx = __builtin_bit_cast(half2v, qv[t][0]);
            const half2v qy = __builtin_bit_cast(half2v, qv[t][1]);
            const half2v qz = __builtin_bit_cast(half2v, qv[t][2]);
            const half2v qw = __builtin_bit_cast(half2v, qv[t][3]);
            acc[(4 * t + 0) % 6] = __builtin_amdgcn_fdot2(qx, ecol[4 * t + 0], acc[(4 * t + 0) % 6], false);
            acc[(4 * t + 1) % 6] = __builtin_amdgcn_fdot2(qy, ecol[4 * t + 1], acc[(4 * t + 1) % 6], false);
            acc[(4 * t + 2) % 6] = __builtin_amdgcn_fdot2(qz, ecol[4 * t + 2], acc[(4 * t + 2) % 6], false);
            acc[(4 * t + 3) % 6] = __builtin_amdgcn_fdot2(qw, ecol[4 * t + 3], acc[(4 * t + 3) % 6], false);
        }
        const float U = ((acc[0] + acc[1]) + (acc[2] + acc[3])) + (acc[4] + acc[5]);

        // exact normalization by the CURRENT buffer's max exponent (K),
        // then multiply by exp(em) (computed off-path from the prefetch)
        const float F = __expf(emA);
        float w = ldexpf(U, -(K + 6)) * F;   // bounded
        if (!active) w = 0.f;
        w = mkA ? w : wreg;                  // masked step: state unchanged
        sumk += mkA ? (K + 6) : 0;
        wreg = w;

        const float wmx = wave_max_all(w);
        if (lane == 0) maxsh[rb][wid] = wmx;
        qsh[rb ^ 1][tid] = (__fp16)w;
        BARRIER();

        // exponent of the exact max of the values just written (for s+1)
        const float r = fmaxf(maxsh[rb][0], maxsh[rb][1]);
        K = (int)((__float_as_uint(r) >> 23) & 255u) - 126;

        emA = emB; emB = emC; emC = emN;
        mkA = mkB; mkB = mkC; mkC = mkN;
    }

    // ---- denominator = M0 + sumk*ln2 + log(sum_j w_j * exp(end_j))
    const float dv = active ? wreg * __expf(endT[jc]) : 0.f;
    {
        const float ws = wave_sum_all(dv);
        if (lane == 0) redd[wid] = ws;
    }
    __syncthreads();
    const float denom = M0 + (float)sumk * LN2 + __logf(redd[0] + redd[1]);

    // ---- numerator: gather along the tag path (128 threads, 4 steps each)
    float nsum = 0.f, msum = 0.f;
    #pragma unroll
    for (int kk = 0; kk < SEQ / NTHR; ++kk) {
        const int s  = tid + NTHR * kk;
        const int tg = tags_b[s];
        const int mk = masks_b[s];
        msum += mk ? 1.f : 0.f;
        if (s == 0) {
            nsum += startT[tg] + em_b[tg];
        } else if (mk) {
            nsum += trans[tags_b[s - 1] * NC + tg] + em_b[s * NC + tg];
        }
    }
    nsum = wave_sum_all(nsum);
    msum = wave_sum_all(msum);
    if (lane == 0) { redn[wid] = nsum; redm[wid] = msum; }
    __syncthreads();
    if (tid == 0) {
        const float numer = redn[0] + redn[1];
        const int   cnt   = (int)(redm[0] + redm[1]);
        const int   last  = tags_b[cnt - 1];
        atomicAdd(out, (numer + endT[last] - denom) * (1.0f / (float)BATCH));
    }
}

extern "C" void kernel_launch(void* const* d_in, const int* in_sizes, int n_in,
                              void* d_out, int out_size, void* d_ws, size_t ws_size,
                              hipStream_t stream) {
    const float* em     = (const float*)d_in[0];
    const int*   tags   = (const int*)  d_in[1];
    const int*   masks  = (const int*)  d_in[2];
    const float* startT = (const float*)d_in[3];
    const float* endT   = (const float*)d_in[4];
    const float* trans  = (const float*)d_in[5];
    float* out = (float*)d_out;

    (void)hipMemsetAsync(out, 0, sizeof(float), stream);
    crf_llh_kernel<<<BATCH, NTHR, 0, stream>>>(em, tags, masks, startT, endT, trans, out);
}